// Round 11
// baseline (107.690 us; speedup 1.0000x reference)
//
#include <hip/hip_runtime.h>
#include <hip/hip_cooperative_groups.h>

namespace cg = cooperative_groups;

// GrowingSignature: truncated iterated-sums signature, levels 1..4, F=4.
// x: (32, 512, 4) f32;  out: (32, 512, 341) f32.
// Single cooperative kernel (R8 bodies fused): phase 1 computes chunk-local
// signatures (CS=32, C=16) into Lsig; grid.sync(); phase 2 Chen-combines the
// prefix from LDS-staged Lsig rows and runs the plain running-signature
// recursion (4 FMA/step; a single-step Chen product only touches level 1).
// Word layout (signatory order): len1 cols 1..4, len2 cols 5..20,
// len3 cols 21..84, len4 cols 85..340; word (a,b,c,e) -> 85+64a+16b+4c+e.

#define SIG_B 32
#define SIG_L 512
#define SIG_NSTEP 511
#define SIG_ROW 341
#define SIG_CS 32            // chunk size (increments)
#define SIG_C 16             // chunks per batch
#define SIG_PAD 344          // padded row stride in workspace (floats, %4==0)

__global__ __launch_bounds__(256) void sigF(const float* __restrict__ x,
                                            float* __restrict__ Lsig,
                                            float* __restrict__ out) {
    const int bc = blockIdx.x;
    const int b = bc / SIG_C, c = bc % SIG_C;
    const int tid = threadIdx.x;
    const int t0 = c * SIG_CS;
    const int nt = min(SIG_CS, SIG_NSTEP - t0);   // 32, or 31 for last chunk

    __shared__ float dlds[SIG_CS * 4];
    __shared__ float L[SIG_C * SIG_PAD];

    // Stage increments d[t][f] = x[t+1][f] - x[t][f] into LDS (used by BOTH phases).
    const float* xb = x + ((size_t)b * SIG_L + t0) * 4;
    if (tid < nt) {
        float4 x0 = *(const float4*)(xb + tid * 4);
        float4 x1 = *(const float4*)(xb + (tid + 1) * 4);
        *(float4*)(dlds + tid * 4) =
            make_float4(x1.x - x0.x, x1.y - x0.y, x1.z - x0.z, x1.w - x0.w);
    }
    __syncthreads();

    const int a = tid >> 6, bb = (tid >> 4) & 3, cc = (tid >> 2) & 3, ee = tid & 3;

    // ---------- Phase 1: chunk-local signature ----------
    {
        float s1 = 0.f, s2 = 0.f, s3 = 0.f, s4 = 0.f;
        const float* dp = dlds;
        for (int t = 0; t < nt; ++t) {
            const float da = dp[a], db = dp[bb], dc = dp[cc], de = dp[ee];
            dp += 4;
            s4 = fmaf(s3, de, s4);  // top level first: consumes pre-update s3
            s3 = fmaf(s2, dc, s3);
            s2 = fmaf(s1, db, s2);
            s1 += da;
        }
        float* Lr = Lsig + (size_t)bc * SIG_PAD;
        if ((tid & 63) == 0) Lr[1 + a] = s1;
        if ((tid & 15) == 0) Lr[5 + (tid >> 4)] = s2;
        if ((tid & 3) == 0)  Lr[21 + (tid >> 2)] = s3;
        Lr[85 + tid] = s4;
    }

    __threadfence();              // publish Lsig device-wide
    cg::this_grid().sync();       // grid barrier (cooperative launch)

    // ---------- Phase 2: stage prefix rows, combine, output scan ----------
    {
        const float4* Lb4 = (const float4*)(Lsig + (size_t)b * SIG_C * SIG_PAD);
        float4* L4p = (float4*)L;
        const int n4 = c * (SIG_PAD / 4);
        for (int i = tid; i < n4; i += 256) L4p[i] = Lb4[i];
    }
    __syncthreads();

    // Chen-combine chunks 0..c-1 -> prefix (p1..p4) for this lane's word.
    float p1 = 0.f, p2 = 0.f, p3 = 0.f, p4 = 0.f;
    for (int j = 0; j < c; ++j) {
        const float* Lc = L + j * SIG_PAD;
        const float l1a = Lc[1 + a], l1b = Lc[1 + bb], l1c = Lc[1 + cc], l1e = Lc[1 + ee];
        const float l2ab = Lc[5 + 4 * a + bb], l2bc = Lc[5 + 4 * bb + cc],
                    l2ce = Lc[5 + 4 * cc + ee];
        const float l3abc = Lc[21 + 16 * a + 4 * bb + cc],
                    l3bce = Lc[21 + 16 * bb + 4 * cc + ee];
        const float l4 = Lc[85 + tid];
        p4 += p3 * l1e + p2 * l2ce + p1 * l3bce + l4;  // uses pre-update p1..p3
        p3 += p2 * l1c + p1 * l2bc + l3abc;
        p2 += p1 * l1b + l2ab;
        p1 += l1a;
    }

    float* row = out + ((size_t)b * SIG_L + (t0 + 1)) * SIG_ROW;

    if (c == 0) {  // row 0: [1, zeros]
        float* r0 = out + (size_t)b * SIG_L * SIG_ROW;
        if (tid == 0)        __builtin_nontemporal_store(1.0f, r0 + 0);
        if ((tid & 63) == 0) __builtin_nontemporal_store(0.f, r0 + 1 + a);
        if ((tid & 15) == 0) __builtin_nontemporal_store(0.f, r0 + 5 + (tid >> 4));
        if ((tid & 3) == 0)  __builtin_nontemporal_store(0.f, r0 + 21 + (tid >> 2));
        __builtin_nontemporal_store(0.f, r0 + 85 + tid);
    }

    // Plain running-signature recursion seeded with the prefix: 4 FMA/step.
    const float* dp = dlds;
    for (int t = 0; t < nt; ++t) {
        const float da = dp[a], db = dp[bb], dc = dp[cc], de = dp[ee];
        dp += 4;
        p4 = fmaf(p3, de, p4);  // top level first: consumes pre-update p3
        p3 = fmaf(p2, dc, p3);
        p2 = fmaf(p1, db, p2);
        p1 += da;

        if (tid == 0)        __builtin_nontemporal_store(1.0f, row + 0);
        if ((tid & 63) == 0) __builtin_nontemporal_store(p1, row + 1 + a);
        if ((tid & 15) == 0) __builtin_nontemporal_store(p2, row + 5 + (tid >> 4));
        if ((tid & 3) == 0)  __builtin_nontemporal_store(p3, row + 21 + (tid >> 2));
        __builtin_nontemporal_store(p4, row + 85 + tid);  // coalesced
        row += SIG_ROW;
    }
}

extern "C" void kernel_launch(void* const* d_in, const int* in_sizes, int n_in,
                              void* d_out, int out_size, void* d_ws, size_t ws_size,
                              hipStream_t stream) {
    const float* x = (const float*)d_in[0];   // (32, 512, 4) f32
    float* out = (float*)d_out;               // (32, 512, 341) f32
    float* Lsig = (float*)d_ws;               // 512 * 344 floats (~0.7 MB)

    void* args[] = {(void*)&x, (void*)&Lsig, (void*)&out};
    hipLaunchCooperativeKernel((void*)sigF, dim3(SIG_B * SIG_C), dim3(256),
                               args, 0, stream);
}

// Round 14
// 80.361 us; speedup vs baseline: 1.3401x; 1.3401x over previous
//
#include <hip/hip_runtime.h>

// GrowingSignature: truncated iterated-sums signature, levels 1..4, F=4.
// x: (32, 512, 4) f32;  out: (32, 512, 341) f32.
// SINGLE dispatch (R8 bodies fused). Phase 1: chunk-local signatures
// (CS=32, C=16) -> Lsig; publish via per-batch release-bitmask. Phase 2:
// spin-acquire bits 0..c-1 of own batch (BOUNDED spin: degrades to wrong
// answer, never a hang), Chen-combine prefix from LDS-staged Lsig rows,
// then plain running-signature scan (4 FMA/step — a single-step Chen
// product only touches level 1). All 512 blocks co-resident (22.5 KB LDS
// -> 7 blocks/CU; 4 waves/block), producers publish before any wait, so
// the intra-batch spin resolves in phase-1 time. (R11: grid.sync()=94us.)
// Word layout (signatory order): len1 cols 1..4, len2 cols 5..20,
// len3 cols 21..84, len4 cols 85..340; word (a,b,c,e) -> 85+64a+16b+4c+e.

#define SIG_B 32
#define SIG_L 512
#define SIG_NSTEP 511
#define SIG_ROW 341
#define SIG_CS 32            // chunk size (increments)
#define SIG_C 16             // chunks per batch
#define SIG_PAD 344          // padded row stride in workspace (floats, %4==0)

__global__ __launch_bounds__(256) void sigFused(
        const float* __restrict__ x,
        unsigned int* __restrict__ flags,   // 32 words, zeroed per call
        float* __restrict__ Lsig,           // 512 * SIG_PAD floats
        float* __restrict__ out) {
    const int bc = blockIdx.x;
    const int b = bc / SIG_C, c = bc % SIG_C;
    const int tid = threadIdx.x;
    const int t0 = c * SIG_CS;
    const int nt = min(SIG_CS, SIG_NSTEP - t0);   // 32, or 31 for c=15

    __shared__ float dlds[SIG_CS * 4];
    __shared__ float L[SIG_C * SIG_PAD];

    // Stage increments once (used by both phases).
    const float* xb = x + ((size_t)b * SIG_L + t0) * 4;
    if (tid < nt) {
        float4 x0 = *(const float4*)(xb + tid * 4);
        float4 x1 = *(const float4*)(xb + (tid + 1) * 4);
        *(float4*)(dlds + tid * 4) =
            make_float4(x1.x - x0.x, x1.y - x0.y, x1.z - x0.z, x1.w - x0.w);
    }
    __syncthreads();

    const int a = tid >> 6, bb = (tid >> 4) & 3, cc = (tid >> 2) & 3, ee = tid & 3;

    // ---------- Phase 1: chunk-local signature (c=15's is never consumed) ----------
    if (c < SIG_C - 1) {
        float s1 = 0.f, s2 = 0.f, s3 = 0.f, s4 = 0.f;
        const float* dp = dlds;
        for (int t = 0; t < SIG_CS; ++t) {        // c<15 => nt==32
            const float da = dp[a], db = dp[bb], dc = dp[cc], de = dp[ee];
            dp += 4;
            s4 = fmaf(s3, de, s4);  // top level first: consumes pre-update s3
            s3 = fmaf(s2, dc, s3);
            s2 = fmaf(s1, db, s2);
            s1 += da;
        }
        float* Lr = Lsig + (size_t)bc * SIG_PAD;
        if ((tid & 63) == 0) Lr[1 + a] = s1;
        if ((tid & 15) == 0) Lr[5 + (tid >> 4)] = s2;
        if ((tid & 3) == 0)  Lr[21 + (tid >> 2)] = s3;
        Lr[85 + tid] = s4;
        __syncthreads();                      // drain this block's Lsig stores
        if (tid == 0) {
            __threadfence();                  // release: publish Lsig
            __hip_atomic_fetch_or(&flags[b], 1u << c, __ATOMIC_RELEASE,
                                  __HIP_MEMORY_SCOPE_AGENT);
        }
    }

    // ---------- Phase 2: acquire chunks 0..c-1, stage, combine ----------
    if (c > 0) {
        if (tid == 0) {
            const unsigned int need = (1u << c) - 1u;
            // Bounded spin: ~1e7 iters (~250 ms) then give up -> visible
            // absmax failure instead of a GPU hang. Never triggers when
            // the co-residency/ordering analysis holds.
            for (int spin = 0; spin < 10000000; ++spin) {
                if ((__hip_atomic_load(&flags[b], __ATOMIC_ACQUIRE,
                                       __HIP_MEMORY_SCOPE_AGENT) & need) == need)
                    break;
                __builtin_amdgcn_s_sleep(2);
            }
            __threadfence();                  // acquire: invalidate L1
        }
        __syncthreads();
        const float4* Lb4 = (const float4*)(Lsig + (size_t)b * SIG_C * SIG_PAD);
        float4* L4p = (float4*)L;
        const int n4 = c * (SIG_PAD / 4);
        for (int i = tid; i < n4; i += 256) L4p[i] = Lb4[i];
        __syncthreads();
    }

    float p1 = 0.f, p2 = 0.f, p3 = 0.f, p4 = 0.f;
    for (int j = 0; j < c; ++j) {
        const float* Lc = L + j * SIG_PAD;
        const float l1a = Lc[1 + a], l1b = Lc[1 + bb], l1c = Lc[1 + cc], l1e = Lc[1 + ee];
        const float l2ab = Lc[5 + 4 * a + bb], l2bc = Lc[5 + 4 * bb + cc],
                    l2ce = Lc[5 + 4 * cc + ee];
        const float l3abc = Lc[21 + 16 * a + 4 * bb + cc],
                    l3bce = Lc[21 + 16 * bb + 4 * cc + ee];
        const float l4 = Lc[85 + tid];
        p4 += p3 * l1e + p2 * l2ce + p1 * l3bce + l4;  // uses pre-update p1..p3
        p3 += p2 * l1c + p1 * l2bc + l3abc;
        p2 += p1 * l1b + l2ab;
        p1 += l1a;
    }

    float* row = out + ((size_t)b * SIG_L + (t0 + 1)) * SIG_ROW;

    if (c == 0) {  // row 0: [1, zeros]
        float* r0 = out + (size_t)b * SIG_L * SIG_ROW;
        if (tid == 0)        __builtin_nontemporal_store(1.0f, r0 + 0);
        if ((tid & 63) == 0) __builtin_nontemporal_store(0.f, r0 + 1 + a);
        if ((tid & 15) == 0) __builtin_nontemporal_store(0.f, r0 + 5 + (tid >> 4));
        if ((tid & 3) == 0)  __builtin_nontemporal_store(0.f, r0 + 21 + (tid >> 2));
        __builtin_nontemporal_store(0.f, r0 + 85 + tid);
    }

    // Plain running-signature recursion seeded with the prefix: 4 FMA/step.
    const float* dp = dlds;
    for (int t = 0; t < nt; ++t) {
        const float da = dp[a], db = dp[bb], dc = dp[cc], de = dp[ee];
        dp += 4;
        p4 = fmaf(p3, de, p4);  // top level first: consumes pre-update p3
        p3 = fmaf(p2, dc, p3);
        p2 = fmaf(p1, db, p2);
        p1 += da;

        if (tid == 0)        __builtin_nontemporal_store(1.0f, row + 0);
        if ((tid & 63) == 0) __builtin_nontemporal_store(p1, row + 1 + a);
        if ((tid & 15) == 0) __builtin_nontemporal_store(p2, row + 5 + (tid >> 4));
        if ((tid & 3) == 0)  __builtin_nontemporal_store(p3, row + 21 + (tid >> 2));
        __builtin_nontemporal_store(p4, row + 85 + tid);  // coalesced
        row += SIG_ROW;
    }
}

extern "C" void kernel_launch(void* const* d_in, const int* in_sizes, int n_in,
                              void* d_out, int out_size, void* d_ws, size_t ws_size,
                              hipStream_t stream) {
    const float* x = (const float*)d_in[0];   // (32, 512, 4) f32
    float* out = (float*)d_out;               // (32, 512, 341) f32

    unsigned int* flags = (unsigned int*)d_ws;               // 32 words
    float* Lsig = (float*)((char*)d_ws + 256);               // 512 * SIG_PAD floats

    hipMemsetAsync(flags, 0, SIG_B * sizeof(unsigned int), stream);
    sigFused<<<SIG_B * SIG_C, 256, 0, stream>>>(x, flags, Lsig, out);
}

// Round 15
// 22.032 us; speedup vs baseline: 4.8879x; 3.6475x over previous
//
#include <hip/hip_runtime.h>

// GrowingSignature: truncated iterated-sums signature, levels 1..4, F=4.
// x: (32, 512, 4) f32;  out: (32, 512, 341) f32.
// 2-kernel chunked scan (CS=32, C=16) — R8 anchor structure. R15 change:
// both 32-step scan loops are constant-trip (32), fully unrolled, with
// zero-padded dlds tail; only the output store is guarded by t<nt. This
// lets the compiler batch ds_read_b32 groups ahead of the FMA chains,
// amortizing LDS latency (R2 calibration: ~333 cyc/step unhidden in the
// runtime-trip version; the serial scan is the wave-latency wall that
// TLP cannot hide for a single block).
// Word layout (signatory order): len1 cols 1..4, len2 cols 5..20,
// len3 cols 21..84, len4 cols 85..340; word (a,b,c,e) -> 85+64a+16b+4c+e.

#define SIG_B 32
#define SIG_L 512
#define SIG_NSTEP 511
#define SIG_ROW 341
#define SIG_CS 32            // chunk size (increments)
#define SIG_C 16             // chunks per batch
#define SIG_PAD 344          // padded row stride in workspace (floats, %4==0)

// ---------- Kernel A: local chunk signatures ----------
__global__ __launch_bounds__(256) void sigA(const float* __restrict__ x,
                                            float* __restrict__ Lsig) {
    const int bc = blockIdx.x;
    const int b = bc / SIG_C, c = bc % SIG_C;
    const int tid = threadIdx.x;
    const int t0 = c * SIG_CS;
    const int nt = min(SIG_CS, SIG_NSTEP - t0);   // 32, or 31 for c=15

    __shared__ float dlds[SIG_CS * 4];
    const float* xb = x + ((size_t)b * SIG_L + t0) * 4;
    if (tid < SIG_CS) {
        float4 d = make_float4(0.f, 0.f, 0.f, 0.f);   // zero-pad tail step
        if (tid < nt) {
            float4 x0 = *(const float4*)(xb + tid * 4);
            float4 x1 = *(const float4*)(xb + (tid + 1) * 4);
            d = make_float4(x1.x - x0.x, x1.y - x0.y, x1.z - x0.z, x1.w - x0.w);
        }
        *(float4*)(dlds + tid * 4) = d;
    }
    __syncthreads();

    const int a = tid >> 6, bb = (tid >> 4) & 3, cc = (tid >> 2) & 3, ee = tid & 3;
    float s1 = 0.f, s2 = 0.f, s3 = 0.f, s4 = 0.f;
#pragma unroll
    for (int t = 0; t < SIG_CS; ++t) {            // constant trip -> full unroll
        const float* dp = dlds + t * 4;
        const float da = dp[a], db = dp[bb], dc = dp[cc], de = dp[ee];
        s4 = fmaf(s3, de, s4);  // top level first: consumes pre-update s3
        s3 = fmaf(s2, dc, s3);
        s2 = fmaf(s1, db, s2);
        s1 += da;
    }
    float* Lr = Lsig + (size_t)bc * SIG_PAD;
    if ((tid & 63) == 0) Lr[1 + a] = s1;
    if ((tid & 15) == 0) Lr[5 + (tid >> 4)] = s2;
    if ((tid & 3) == 0)  Lr[21 + (tid >> 2)] = s3;
    Lr[85 + tid] = s4;
}

// ---------- Kernel C: prefix combine + plain running-signature scan ----------
__global__ __launch_bounds__(256) void sigC(const float* __restrict__ x,
                                            const float* __restrict__ Lsig,
                                            float* __restrict__ out) {
    const int bc = blockIdx.x;
    const int b = bc / SIG_C, c = bc % SIG_C;
    const int tid = threadIdx.x;
    const int t0 = c * SIG_CS;
    const int nt = min(SIG_CS, SIG_NSTEP - t0);

    __shared__ float dlds[SIG_CS * 4];
    __shared__ float L[SIG_C * SIG_PAD];

    const float* xb = x + ((size_t)b * SIG_L + t0) * 4;
    if (tid < SIG_CS) {
        float4 d = make_float4(0.f, 0.f, 0.f, 0.f);   // zero-pad tail step
        if (tid < nt) {
            float4 x0 = *(const float4*)(xb + tid * 4);
            float4 x1 = *(const float4*)(xb + (tid + 1) * 4);
            d = make_float4(x1.x - x0.x, x1.y - x0.y, x1.z - x0.z, x1.w - x0.w);
        }
        *(float4*)(dlds + tid * 4) = d;
    }
    // Stage the c preceding chunk signatures (only what this block combines).
    {
        const float4* Lb4 = (const float4*)(Lsig + (size_t)b * SIG_C * SIG_PAD);
        float4* L4p = (float4*)L;
        const int n4 = c * (SIG_PAD / 4);
        for (int i = tid; i < n4; i += 256) L4p[i] = Lb4[i];
    }
    __syncthreads();

    const int a = tid >> 6, bb = (tid >> 4) & 3, cc = (tid >> 2) & 3, ee = tid & 3;

    // Chen-combine chunks 0..c-1 -> prefix (p1..p4) for this lane's word.
    float p1 = 0.f, p2 = 0.f, p3 = 0.f, p4 = 0.f;
    for (int j = 0; j < c; ++j) {
        const float* Lc = L + j * SIG_PAD;
        const float l1a = Lc[1 + a], l1b = Lc[1 + bb], l1c = Lc[1 + cc], l1e = Lc[1 + ee];
        const float l2ab = Lc[5 + 4 * a + bb], l2bc = Lc[5 + 4 * bb + cc],
                    l2ce = Lc[5 + 4 * cc + ee];
        const float l3abc = Lc[21 + 16 * a + 4 * bb + cc],
                    l3bce = Lc[21 + 16 * bb + 4 * cc + ee];
        const float l4 = Lc[85 + tid];
        p4 += p3 * l1e + p2 * l2ce + p1 * l3bce + l4;  // uses pre-update p1..p3
        p3 += p2 * l1c + p1 * l2bc + l3abc;
        p2 += p1 * l1b + l2ab;
        p1 += l1a;
    }

    float* row = out + ((size_t)b * SIG_L + (t0 + 1)) * SIG_ROW;

    if (c == 0) {  // row 0: [1, zeros]
        float* r0 = out + (size_t)b * SIG_L * SIG_ROW;
        if (tid == 0)        __builtin_nontemporal_store(1.0f, r0 + 0);
        if ((tid & 63) == 0) __builtin_nontemporal_store(0.f, r0 + 1 + a);
        if ((tid & 15) == 0) __builtin_nontemporal_store(0.f, r0 + 5 + (tid >> 4));
        if ((tid & 3) == 0)  __builtin_nontemporal_store(0.f, r0 + 21 + (tid >> 2));
        __builtin_nontemporal_store(0.f, r0 + 85 + tid);
    }

    // Plain running-signature recursion seeded with the prefix: 4 FMA/step.
    // Constant-trip unroll; step 31 of c=15 computes on zero-pad (state
    // unchanged) and its store is skipped by the uniform t<nt guard.
#pragma unroll
    for (int t = 0; t < SIG_CS; ++t) {
        const float* dp = dlds + t * 4;
        const float da = dp[a], db = dp[bb], dc = dp[cc], de = dp[ee];
        p4 = fmaf(p3, de, p4);  // top level first: consumes pre-update p3
        p3 = fmaf(p2, dc, p3);
        p2 = fmaf(p1, db, p2);
        p1 += da;

        if (t < nt) {
            float* r = row + (size_t)t * SIG_ROW;
            if (tid == 0)        __builtin_nontemporal_store(1.0f, r + 0);
            if ((tid & 63) == 0) __builtin_nontemporal_store(p1, r + 1 + a);
            if ((tid & 15) == 0) __builtin_nontemporal_store(p2, r + 5 + (tid >> 4));
            if ((tid & 3) == 0)  __builtin_nontemporal_store(p3, r + 21 + (tid >> 2));
            __builtin_nontemporal_store(p4, r + 85 + tid);  // coalesced
        }
    }
}

extern "C" void kernel_launch(void* const* d_in, const int* in_sizes, int n_in,
                              void* d_out, int out_size, void* d_ws, size_t ws_size,
                              hipStream_t stream) {
    const float* x = (const float*)d_in[0];   // (32, 512, 4) f32
    float* out = (float*)d_out;               // (32, 512, 341) f32
    float* Lsig = (float*)d_ws;               // 512 * 344 floats

    sigA<<<SIG_B * SIG_C, 256, 0, stream>>>(x, Lsig);
    sigC<<<SIG_B * SIG_C, 256, 0, stream>>>(x, Lsig, out);
}